// Round 3
// baseline (916.436 us; speedup 1.0000x reference)
//
#include <hip/hip_runtime.h>
#include <hip/hip_bf16.h>
#include <math.h>

// Problem constants (B=4, T=1024, H=1024, V=32000)
constexpr int kH   = 1024;
constexpr int kV   = 32000;
constexpr int kTok = 4096;    // B*T
constexpr int BM   = 256;
constexpr int BN   = 256;
constexpr int BK   = 64;      // f16 elements per K-step
constexpr int NT   = kH / BK;    // 16 K-tiles
constexpr int NVT  = kV / BN;    // 125
constexpr int NMT  = kTok / BM;  // 16

typedef _Float16 f16x8  __attribute__((ext_vector_type(8)));
typedef float    f32x16 __attribute__((ext_vector_type(16)));

typedef __attribute__((address_space(1))) const void gvoid_t;
typedef __attribute__((address_space(3))) void lvoid_t;

// fp32 -> f16 with XOR-swizzled 16B blocks: within each 64-elem K-chunk,
// logical block c of row r lands at physical block c ^ (r & 7). GEMM staging
// stays linear (global_load_lds requirement) while ds_read_b128 fragment reads
// spread across bank groups (measured 0 conflicts).
__global__ __launch_bounds__(256) void convert_kernel(
    const float* __restrict__ src, _Float16* __restrict__ dst)
{
  int idx = blockIdx.x * 256 + threadIdx.x;   // one 8-elem block per thread
  int row = idx >> 7;                          // kH/8 = 128 blocks per row
  int blk = idx & 127;
  int chunk = blk >> 3;                        // 64-elem chunk (16 per row)
  int c = blk & 7;
  int p = c ^ (row & 7);
  const float* s = src + ((size_t)row << 10) + (blk << 3);
  float4 v0 = *(const float4*)s;
  float4 v1 = *(const float4*)(s + 4);
  f16x8 o = { (_Float16)v0.x, (_Float16)v0.y, (_Float16)v0.z, (_Float16)v0.w,
              (_Float16)v1.x, (_Float16)v1.y, (_Float16)v1.z, (_Float16)v1.w };
  *(f16x8*)&dst[((size_t)row << 10) + (chunk << 6) + (p << 3)] = o;
}

// ---------------------------------------------------------------------------
// Fused GEMM + per-row (max, sum-exp) partials over each 256-col vocab tile.
// 256x256 tile, BK=64, 8 waves (2 tok-halves x 4 voc-quarters), per-wave
// output 64 voc x 128 tok via mfma_f32_32x32x16_f16 with SWAPPED operands
// (A-operand = vocab rows, B-operand = token cols) -> acc[2 voc][4 tok] x16.
// Pipeline: phase g's ds_reads fetch fragments for phase g+1; MFMA g uses
// fragments read at g-1, so LDS pipe drains under the MFMA cluster (no
// per-phase lgkmcnt(0) serialization). Staging: region-death schedule,
// vmcnt(6) once per K-tile; vf (B-side) loaded to registers once per tile in
// the post-MFMA slot of phase 3.
// ---------------------------------------------------------------------------
__global__ __launch_bounds__(512, 2) void lse_gemm_kernel(
    const _Float16* __restrict__ X0, const _Float16* __restrict__ W0,
    const _Float16* __restrict__ X1, const _Float16* __restrict__ W1,
    float2* __restrict__ P0, float2* __restrict__ P1)
{
  __shared__ _Float16 lds[2][2][BM * BK];   // [buf][A=0 tok / B=1 voc] = 128 KB

  const _Float16* Xp = blockIdx.z ? X1 : X0;
  const _Float16* Wp = blockIdx.z ? W1 : W0;
  float2* Pp = blockIdx.z ? P1 : P0;

  const int tid  = threadIdx.x;
  const int wave = tid >> 6;
  const int lane = tid & 63;
  const int l31  = lane & 31;
  const int h    = lane >> 5;        // k-half within K=16 step
  const int ll7  = lane & 7;         // == (row & 7) for all fragment rows
  const int wr   = wave >> 2;        // 0..1 : token half (128 tokens)
  const int wc   = wave & 3;         // 0..3 : vocab quarter (64 rows)
  const int srow = lane >> 3;        // staging row within 8-row group
  const int sblk = lane & 7;         // staging 16B block within row chunk

  const int m_base = blockIdx.x * BM;
  const int v_base = blockIdx.y * BN;

  // Staging base pointers: each load covers 8 rows x 128B (one wave = 1KB).
  const _Float16* gA = Xp + (size_t)(m_base + wave * 8 + srow) * kH + sblk * 8;
  const _Float16* gB = Wp + (size_t)(v_base + wave * 8 + srow) * kH + sblk * 8;

  // Fragment addressing (f16 units). Row stride in LDS = BK = 64 f16 = 128B.
  // K-step s, k-half h: logical 16B block = s*2+h, physical = (s*2+h)^(row&7),
  // and row&7 == ll7 for every fragment row.
  const int baseA = (wr * 128 + l31) * BK;   // + f*2048 + offK[s]
  const int baseV = (wc * 64  + l31) * BK;   // + j*2048 + offK[s]
  int offK[4];
#pragma unroll
  for (int s = 0; s < 4; ++s) offK[s] = (((s * 2 + h) ^ ll7) << 3);

  f32x16 acc[2][4];
#pragma unroll
  for (int j = 0; j < 2; ++j)
#pragma unroll
    for (int i = 0; i < 4; ++i)
#pragma unroll
      for (int r = 0; r < 16; ++r) acc[j][i][r] = 0.f;

  f16x8 vf[2][4];          // vocab fragments: whole tile's B-side, in regs
  f16x8 tfa[4], tfb[4];    // token fragment double-buffer (one frag x 4 K-steps)

#define STG_A(c, kt, hh) do {                                                       \
    __builtin_amdgcn_global_load_lds(                                               \
        (gvoid_t*)(gA + (size_t)((hh) * 128     ) * kH + (kt) * BK),                \
        (lvoid_t*)&lds[c][0][(((hh) * 128     ) + wave * 8) * BK], 16, 0, 0);       \
    __builtin_amdgcn_global_load_lds(                                               \
        (gvoid_t*)(gA + (size_t)((hh) * 128 + 64) * kH + (kt) * BK),                \
        (lvoid_t*)&lds[c][0][(((hh) * 128 + 64) + wave * 8) * BK], 16, 0, 0);       \
  } while (0)
#define STG_B(c, kt, hh) do {                                                       \
    __builtin_amdgcn_global_load_lds(                                               \
        (gvoid_t*)(gB + (size_t)((hh) * 128     ) * kH + (kt) * BK),                \
        (lvoid_t*)&lds[c][1][(((hh) * 128     ) + wave * 8) * BK], 16, 0, 0);       \
    __builtin_amdgcn_global_load_lds(                                               \
        (gvoid_t*)(gB + (size_t)((hh) * 128 + 64) * kH + (kt) * BK),                \
        (lvoid_t*)&lds[c][1][(((hh) * 128 + 64) + wave * 8) * BK], 16, 0, 0);       \
  } while (0)

// Barrier with compiler memory fences on both sides: the post-barrier
// prefetch ds_reads must not be hoisted above it (phase-3 reads target
// freshly vmcnt'd LDS), and pre-barrier reads must not sink below.
#define BAR do { asm volatile("" ::: "memory");                                     \
                 __builtin_amdgcn_s_barrier();                                      \
                 asm volatile("" ::: "memory"); } while (0)
#define VM6  asm volatile("s_waitcnt vmcnt(6)" ::: "memory")
#define VM0  asm volatile("s_waitcnt vmcnt(0)" ::: "memory")

#define RDTF(dst, c, f) do {                                                        \
    _Pragma("unroll")                                                               \
    for (int s = 0; s < 4; ++s)                                                     \
      dst[s] = *(const f16x8*)&lds[c][0][baseA + (f) * 2048 + offK[s]];             \
  } while (0)
#define RDVF(c) do {                                                                \
    _Pragma("unroll")                                                               \
    for (int j = 0; j < 2; ++j)                                                     \
      _Pragma("unroll")                                                             \
      for (int s = 0; s < 4; ++s)                                                   \
        vf[j][s] = *(const f16x8*)&lds[c][1][baseV + j * 2048 + offK[s]];           \
  } while (0)

// MFMA cluster for token frag g: 8 x mfma_32x32x16, two interleaved acc chains.
#define MM(g, TF) do {                                                              \
    __builtin_amdgcn_s_setprio(1);                                                  \
    _Pragma("unroll")                                                               \
    for (int s = 0; s < 4; ++s) {                                                   \
      acc[0][g] = __builtin_amdgcn_mfma_f32_32x32x16_f16(vf[0][s], TF[s], acc[0][g], 0, 0, 0); \
      acc[1][g] = __builtin_amdgcn_mfma_f32_32x32x16_f16(vf[1][s], TF[s], acc[1][g], 0, 0, 0); \
    }                                                                               \
    __builtin_amdgcn_s_setprio(0);                                                  \
  } while (0)

  // Prologue: tile0 complete (buf0) + tile1 B0,B1,A0 (buf1) = 7 half-tiles.
  STG_B(0, 0, 0); STG_B(0, 0, 1); STG_A(0, 0, 0); STG_A(0, 0, 1);
  STG_B(1, 1, 0); STG_B(1, 1, 1); STG_A(1, 1, 0);
  VM6;                               // tile0 landed; tile1's 3 in flight
  BAR;
  RDVF(0);                           // whole-tile vocab frags -> regs
  RDTF(tfa, 0, 0);                   // token frag 0

  for (int kt = 0; kt < NT - 2; kt += 2) {
    // ---- tile kt (buf0) ----
    STG_A(1, kt + 1, 1); BAR; RDTF(tfb, 0, 1); MM(0, tfa); BAR;
    STG_B(0, kt + 2, 0); BAR; RDTF(tfa, 0, 2); MM(1, tfb); BAR;
    STG_B(0, kt + 2, 1); BAR; RDTF(tfb, 0, 3); MM(2, tfa); BAR;
    STG_A(0, kt + 2, 0); VM6; BAR; RDTF(tfa, 1, 0); MM(3, tfb); RDVF(1); BAR;
    // ---- tile kt+1 (buf1) ----
    STG_A(0, kt + 2, 1); BAR; RDTF(tfb, 1, 1); MM(0, tfa); BAR;
    STG_B(1, kt + 3, 0); BAR; RDTF(tfa, 1, 2); MM(1, tfb); BAR;
    STG_B(1, kt + 3, 1); BAR; RDTF(tfb, 1, 3); MM(2, tfa); BAR;
    STG_A(1, kt + 3, 0); VM6; BAR; RDTF(tfa, 0, 0); MM(3, tfb); RDVF(0); BAR;
  }

  // ---- tail: tile NT-2 (buf0), tile NT-1 (buf1) ----
  STG_A(1, NT - 1, 1); BAR; RDTF(tfb, 0, 1); MM(0, tfa); BAR;
  BAR;                      RDTF(tfa, 0, 2); MM(1, tfb); BAR;
  BAR;                      RDTF(tfb, 0, 3); MM(2, tfa); BAR;
  VM0; BAR;                 RDTF(tfa, 1, 0); MM(3, tfb); RDVF(1); BAR;
  BAR;                      RDTF(tfb, 1, 1); MM(0, tfa); BAR;
  BAR;                      RDTF(tfa, 1, 2); MM(1, tfb); BAR;
  BAR;                      RDTF(tfb, 1, 3); MM(2, tfa); BAR;
  BAR;                                       MM(3, tfb);

#undef STG_A
#undef STG_B
#undef RDTF
#undef RDVF
#undef MM

  // Epilogue. acc[j][i][reg] = logits[vocab = v_base + wc*64 + j*32 + rr]
  //                                  [token = m_base + wr*128 + i*32 + l31]
  // with rr = (reg&3) + 8*(reg>>2) + 4*h. Lane l and l^32 share the token and
  // cover complementary vocab rows -> 32 local values + one xor-32 combine.
  float* redm = (float*)&lds[0][0][0];   // [4 wc][256 tok]
  float* reds = redm + 4 * 256;

#pragma unroll
  for (int i = 0; i < 4; ++i) {
    float m = acc[0][i][0];
#pragma unroll
    for (int r = 1; r < 16; ++r) m = fmaxf(m, acc[0][i][r]);
#pragma unroll
    for (int r = 0; r < 16; ++r) m = fmaxf(m, acc[1][i][r]);
    float s = 0.f;
#pragma unroll
    for (int r = 0; r < 16; ++r) s += __expf(acc[0][i][r] - m);
#pragma unroll
    for (int r = 0; r < 16; ++r) s += __expf(acc[1][i][r] - m);
    float om = __shfl_xor(m, 32, 64);
    float os = __shfl_xor(s, 32, 64);
    float nm = fmaxf(m, om);
    s = s * __expf(m - nm) + os * __expf(om - nm);
    m = nm;
    if (lane < 32) {
      redm[wc * 256 + wr * 128 + i * 32 + lane] = m;
      reds[wc * 256 + wr * 128 + i * 32 + lane] = s;
    }
  }
  __syncthreads();
  if (tid < 256) {
    float M = redm[tid], S = reds[tid];
#pragma unroll
    for (int w = 1; w < 4; ++w) {
      float m2 = redm[w * 256 + tid], s2 = reds[w * 256 + tid];
      float nm = fmaxf(M, m2);
      S = S * __expf(M - nm) + s2 * __expf(m2 - nm);
      M = nm;
    }
    Pp[(size_t)blockIdx.y * kTok + m_base + tid] = make_float2(M, S);
  }
}

// Exact fp32 selected-logit from the ORIGINAL fp32 inputs.
__global__ __launch_bounds__(256) void sel_kernel(
    const float* __restrict__ X0, const float* __restrict__ W0,
    const float* __restrict__ X1, const float* __restrict__ W1,
    const int* __restrict__ ids, float* __restrict__ sel0, float* __restrict__ sel1)
{
  const int model = blockIdx.y;
  const float* X = model ? X1 : X0;
  const float* W = model ? W1 : W0;
  float* out = model ? sel1 : sel0;
  const int wave = threadIdx.x >> 6, lane = threadIdx.x & 63;
  const int t  = blockIdx.x * 4 + wave;
  const int id = ids[t];
  const float* xr = X + (size_t)t * kH;
  const float* wr = W + (size_t)id * kH;
  float s = 0.f;
#pragma unroll
  for (int r = 0; r < 4; ++r) {
    int idx = r * 256 + lane * 4;
    float4 a = *(const float4*)&xr[idx];
    float4 b = *(const float4*)&wr[idx];
    s += a.x * b.x + a.y * b.y + a.z * b.z + a.w * b.w;
  }
#pragma unroll
  for (int st = 32; st; st >>= 1) s += __shfl_xor(s, st, 64);
  if (lane == 0) out[t] = s;
}

// Combine 125 partials/model -> lse; GRPO loss; reduce.
__global__ __launch_bounds__(256) void finalize_kernel(
    const float2* __restrict__ P0, const float2* __restrict__ P1,
    const float* __restrict__ sel0, const float* __restrict__ sel1,
    const float* __restrict__ adv, const int* __restrict__ mask,
    float* __restrict__ accum)
{
  const int t = blockIdx.x * 256 + threadIdx.x;
  float M0 = -INFINITY, S0 = 0.f, M1 = -INFINITY, S1 = 0.f;
  for (int i = 0; i < NVT; ++i) {
    float2 p = P0[(size_t)i * kTok + t];
    if (p.x > M0) { S0 = S0 * __expf(M0 - p.x) + p.y; M0 = p.x; }
    else          { S0 += p.y * __expf(p.x - M0); }
  }
  for (int i = 0; i < NVT; ++i) {
    float2 p = P1[(size_t)i * kTok + t];
    if (p.x > M1) { S1 = S1 * __expf(M1 - p.x) + p.y; M1 = p.x; }
    else          { S1 += p.y * __expf(p.x - M1); }
  }
  float lse0  = M0 + logf(S0);
  float lse1  = M1 + logf(S1);
  float logp  = sel0[t] - lse0;
  float rlogp = sel1[t] - lse1;
  float d  = rlogp - logp;
  float kl = __expf(d) - d - 1.f;
  // coef_1 = exp(logp - stopgrad(logp)) == 1, clip == 1 -> loss = -adv + beta*kl
  float a  = adv[t >> 10];
  float mv = (float)mask[t];
  float loss = (-a + 0.1f * kl) * mv;

#pragma unroll
  for (int st = 32; st; st >>= 1) {
    loss += __shfl_xor(loss, st, 64);
    mv   += __shfl_xor(mv, st, 64);
  }
  __shared__ float lsum[4], msum[4];
  const int wave = threadIdx.x >> 6, lane = threadIdx.x & 63;
  if (lane == 0) { lsum[wave] = loss; msum[wave] = mv; }
  __syncthreads();
  if (threadIdx.x == 0) {
    atomicAdd(&accum[0], lsum[0] + lsum[1] + lsum[2] + lsum[3]);
    atomicAdd(&accum[1], msum[0] + msum[1] + msum[2] + msum[3]);
  }
}

__global__ void scalar_kernel(const float* __restrict__ accum, float* __restrict__ out)
{
  out[0] = accum[0] / fmaxf(accum[1], 1.f);
}

extern "C" void kernel_launch(void* const* d_in, const int* in_sizes, int n_in,
                              void* d_out, int out_size, void* d_ws, size_t ws_size,
                              hipStream_t stream)
{
  const float* x    = (const float*)d_in[0];
  const float* w    = (const float*)d_in[1];
  const float* rx   = (const float*)d_in[2];
  const float* rw   = (const float*)d_in[3];
  const float* adv  = (const float*)d_in[4];
  const int*   ids  = (const int*)d_in[5];
  const int*   mask = (const int*)d_in[6];
  float* out = (float*)d_out;

  // Workspace layout (~152 MB): f16 copies + partials + sel + accum.
  char* ws = (char*)d_ws;
  _Float16* Xh  = (_Float16*)ws;                         // 8 MB
  _Float16* Wh  = Xh + (size_t)kTok * kH;                // 64 MB
  _Float16* RXh = Wh + (size_t)kV * kH;                  // 8 MB
  _Float16* RWh = RXh + (size_t)kTok * kH;               // 64 MB
  float2*   P0  = (float2*)(RWh + (size_t)kV * kH);      // 4 MB
  float2*   P1  = P0 + (size_t)NVT * kTok;               // 4 MB
  float*    sel0 = (float*)(P1 + (size_t)NVT * kTok);
  float*    sel1 = sel0 + kTok;
  float*    accum = sel1 + kTok;

  hipMemsetAsync(accum, 0, 2 * sizeof(float), stream);

  convert_kernel<<<kTok * 128 / 256, 256, 0, stream>>>(x,  Xh);
  convert_kernel<<<kV   * 128 / 256, 256, 0, stream>>>(w,  Wh);
  convert_kernel<<<kTok * 128 / 256, 256, 0, stream>>>(rx, RXh);
  convert_kernel<<<kV   * 128 / 256, 256, 0, stream>>>(rw, RWh);

  sel_kernel<<<dim3(kTok / 4, 2), 256, 0, stream>>>(x, w, rx, rw, ids, sel0, sel1);

  lse_gemm_kernel<<<dim3(NMT, NVT, 2), 512, 0, stream>>>(Xh, Wh, RXh, RWh, P0, P1);

  finalize_kernel<<<kTok / 256, 256, 0, stream>>>(P0, P1, sel0, sel1, adv, mask, accum);
  scalar_kernel<<<1, 1, 0, stream>>>(accum, out);
}